// Round 1
// baseline (575.569 us; speedup 1.0000x reference)
//
#include <hip/hip_runtime.h>

typedef unsigned short u16;
typedef __bf16 bf16x8 __attribute__((ext_vector_type(8)));
typedef float f32x4 __attribute__((ext_vector_type(4)));
typedef u16 u16x8 __attribute__((ext_vector_type(8)));

// ---------- helpers ----------
__device__ __forceinline__ u16 f2bf(float f) {
  unsigned u = __builtin_bit_cast(unsigned, f);
  return (u16)((u + 0x7fffu + ((u >> 16) & 1u)) >> 16);
}

__device__ __forceinline__ void async_load16(const void* g, void* l) {
  __builtin_amdgcn_global_load_lds((const __attribute__((address_space(1))) void*)g,
                                   (__attribute__((address_space(3))) void*)l,
                                   16, 0, 0);
}

// ---------- pad + cast x: (1024,784) f32 -> (1024,832) bf16 ----------
// Kp0 = 832 = 13 * 64 so the 256^2/BK=64 GEMM gets whole K-tiles.
__global__ void pad_x_k(const float* __restrict__ x, u16* __restrict__ xbf) {
  int idx = blockIdx.x * 256 + threadIdx.x;          // 1024*832
  int m = idx / 832, k = idx - m * 832;
  float v = (k < 784) ? x[m * 784 + k] : 0.f;
  xbf[idx] = f2bf(v);
}

// ---------- fused sample + transpose into GEMM-tiled layout ----------
// NEW layout (BK=64 tiles): wt[s][kb64][n][kk], kk in [0,64), bf16.
// Block kb32 writes the (kb32&1) 32-k half of tile kb32>>1. Everything else
// identical to the verified round-0 kernel (same reads, same math).
__global__ __launch_bounds__(256) void sample_wt_k(
    const float* __restrict__ we,   // chunk base: (SC,K,N)
    const float* __restrict__ wm,   // (K,N)
    const float* __restrict__ wv,   // (K,N)
    u16* __restrict__ wt,           // (SC,KB64,1024,64)
    int K, int KB, int SC) {
  const int N = 1024;
  const int b = blockIdx.x;
  int s, kb, nb;
  if (SC >= 8) {
    int g = b & 7, r = b >> 3, spq = SC >> 3;
    int sq = r % spq, r2 = r / spq;
    nb = r2 & 3; kb = r2 >> 2;
    s = g + sq * 8;
  } else {
    s = b % SC; int r = b / SC; nb = r & 3; kb = r >> 2;
  }
  const int t = threadIdx.x;
  const int n = nb * 256 + t;
  const int kbase = kb * 32;
  const int KB64 = (KB + 1) >> 1;
  const float* we_s = we + (size_t)s * K * N;

  u16 pk[32];
#pragma unroll
  for (int jo = 0; jo < 4; ++jo) {
    float v[8];
#pragma unroll
    for (int j = 0; j < 8; ++j) {
      int k = kbase + jo * 8 + j;
      v[j] = 0.f;
      if (k < K) {
        size_t idx = (size_t)k * N + n;
        v[j] = fmaf(__expf(0.5f * wv[idx]), we_s[idx], wm[idx]);
      }
    }
#pragma unroll
    for (int j = 0; j < 8; ++j) pk[jo * 8 + j] = f2bf(v[j]);
  }
  u16* dst = wt + (((size_t)s * KB64 + (kb >> 1)) * 1024 + n) * 64 + (kb & 1) * 32;
#pragma unroll
  for (int q = 0; q < 4; ++q)
    *(u16x8*)(dst + q * 8) = *(const u16x8*)(pk + q * 8);
}

// ---------- sample last-layer W -> Wlt[s][16][1024] bf16 (n>=10 zero) ----------
__global__ void sample_wl_k(const float* __restrict__ wel,  // chunk base (SC,1024,10)
                            const float* __restrict__ wlm,  // (1024,10)
                            const float* __restrict__ wlv,  // (1024,10)
                            u16* __restrict__ wlt) {        // (SC,16,1024)
  int idx = blockIdx.x * 256 + threadIdx.x;   // SC*16*1024
  int k = idx & 1023;
  int n = (idx >> 10) & 15;
  int s = idx >> 14;
  float v = 0.f;
  if (n < 10) {
    size_t i2 = ((size_t)s * 1024 + k) * 10 + n;
    size_t iw = (size_t)k * 10 + n;
    v = fmaf(__expf(0.5f * wlv[iw]), wel[i2], wlm[iw]);
  }
  wlt[idx] = f2bf(v);
}

// ---------- batched GEMM: C[s] = relu(A[s] @ W[s] + bias[s]) ----------
// 256x256 tile, BK=64, 512 threads = 8 waves (2M x 4N), double-buffered
// 128 KiB LDS, global_load_lds staging with counted vmcnt(8) across raw
// s_barriers (loads for K-tile T+1 stay in flight while computing T), LDS
// XOR-swizzle (chunk ^= (chunk>>3)&7 i.e. byte ^= ((byte>>7)&7)<<4) applied
// identically on the staging SOURCE and the ds_read address (both-sides
// involution) -> row-stride-128B ds_read_b128 goes 16-way -> 2-way (free).
// Grid = 16*SC (1 block/CU at SC=16). XCD lane: sample -> XCD s%8, matching
// the sampler's writes.
__global__ __launch_bounds__(512, 2) void gemm_bt_relu(
    const u16* __restrict__ A, size_t strideAs, int ldA,
    const u16* __restrict__ Bt,   // (SC, Kp/64, 1024, 64) bf16 tiles
    u16* __restrict__ C,
    int Kp,
    const float* __restrict__ bm, const float* __restrict__ bv,
    const float* __restrict__ be, int s_off, int SC) {
  // [buf][256][64] A at elem 0, B at elem 32768; per-tile 16384 u16 (32 KiB)
  __shared__ __align__(16) u16 lds[65536];   // 128 KiB

  const int b = blockIdx.x;
  int sc, tile;
  if (SC >= 8) { int g = b & 7, r = b >> 3; tile = r & 15; sc = g + ((r >> 4) << 3); }
  else         { sc = b >> 4; tile = b & 15; }
  const int sg = sc + s_off;
  const u16* A_s = A + (size_t)sc * strideAs;
  const u16* B_s = Bt + (size_t)sc * (size_t)1024 * Kp;
  u16* C_s = C + (size_t)sc * (size_t)1024 * 1024;
  const int m0 = (tile >> 2) * 256;
  const int n0 = (tile & 3) * 256;
  const int t = threadIdx.x;
  const int wid = t >> 6, lane = t & 63;
  const int quad = lane >> 4, lane16 = lane & 15;
  const int wm2 = wid >> 2, wn4 = wid & 3;
  const int NT = Kp >> 6;

  // stage one K-tile (A: 256x64, B: 256x64) -> buf; 8 global_load_lds / wave.
  // LDS dest is linear (wave-uniform base + lane*16); the 16B-chunk swizzle
  // is applied on the per-lane GLOBAL source address instead.
  auto stage = [&](int kt, int buf) {
    const int k0 = kt * 64;
#pragma unroll
    for (int r = 0; r < 4; ++r) {
      int c = r * 512 + t;
      int cl = c ^ ((c >> 3) & 7);
      const u16* srcA = A_s + (size_t)(m0 + (cl >> 3)) * ldA + k0 + (cl & 7) * 8;
      async_load16(srcA, &lds[buf * 16384 + (r * 512 + wid * 64) * 8]);
    }
    const u16* Bk = B_s + (size_t)kt * (1024 * 64);
#pragma unroll
    for (int r = 0; r < 4; ++r) {
      int c = r * 512 + t;
      int cl = c ^ ((c >> 3) & 7);
      const u16* srcB = Bk + (size_t)(n0 + (cl >> 3)) * 64 + (cl & 7) * 8;
      async_load16(srcB, &lds[32768 + buf * 16384 + (r * 512 + wid * 64) * 8]);
    }
  };

  auto rdA = [&](int buf, int mi, int ks) -> bf16x8 {
    int o = (wm2 * 128 + mi * 16 + lane16) * 128 + ks * 64 + quad * 16;
    o ^= ((o >> 7) & 7) << 4;
    return *(const bf16x8*)((const char*)&lds[buf * 16384] + o);
  };
  auto rdB = [&](int buf, int ni, int ks) -> bf16x8 {
    int o = (wn4 * 64 + ni * 16 + lane16) * 128 + ks * 64 + quad * 16;
    o ^= ((o >> 7) & 7) << 4;
    return *(const bf16x8*)((const char*)&lds[32768 + buf * 16384] + o);
  };

  f32x4 acc[8][4];
#pragma unroll
  for (int i = 0; i < 8; ++i)
#pragma unroll
    for (int j = 0; j < 4; ++j) acc[i][j] = (f32x4){0.f, 0.f, 0.f, 0.f};

  stage(0, 0);
  stage(1, 1);
  asm volatile("s_waitcnt vmcnt(8)" ::: "memory");   // tile 0 landed (mine)
  __builtin_amdgcn_s_barrier();                      // visible to all waves

  for (int T = 0; T < NT; ++T) {
    const int cur = T & 1;
    bf16x8 af[4], bb[4];
#pragma unroll
    for (int ks = 0; ks < 2; ++ks) {
#pragma unroll
      for (int i = 0; i < 4; ++i) bb[i] = rdB(cur, i, ks);
#pragma unroll
      for (int i = 0; i < 4; ++i) af[i] = rdA(cur, i, ks);
      __builtin_amdgcn_s_setprio(1);
#pragma unroll
      for (int mi = 0; mi < 4; ++mi)
#pragma unroll
        for (int ni = 0; ni < 4; ++ni)
          acc[mi][ni] =
              __builtin_amdgcn_mfma_f32_16x16x32_bf16(af[mi], bb[ni], acc[mi][ni], 0, 0, 0);
      __builtin_amdgcn_s_setprio(0);
#pragma unroll
      for (int i = 0; i < 4; ++i) af[i] = rdA(cur, 4 + i, ks);
      __builtin_amdgcn_s_setprio(1);
#pragma unroll
      for (int mi = 0; mi < 4; ++mi)
#pragma unroll
        for (int ni = 0; ni < 4; ++ni)
          acc[4 + mi][ni] =
              __builtin_amdgcn_mfma_f32_16x16x32_bf16(af[mi], bb[ni], acc[4 + mi][ni], 0, 0, 0);
      __builtin_amdgcn_s_setprio(0);
    }
    __builtin_amdgcn_sched_barrier(0);     // keep all buf[cur] reads above
    __builtin_amdgcn_s_barrier();          // all waves done reading buf[cur]
    if (T + 2 < NT) stage(T + 2, cur);     // overwrite just-freed buffer
    if (T + 1 < NT) {
      if (T + 2 < NT) asm volatile("s_waitcnt vmcnt(8)" ::: "memory");  // T+1 done
      else            asm volatile("s_waitcnt vmcnt(0)" ::: "memory");
      __builtin_amdgcn_s_barrier();        // tile T+1 visible to all
      __builtin_amdgcn_sched_barrier(0);
    }
  }

  // epilogue: bias (sampled on the fly) + relu + bf16 store
#pragma unroll
  for (int ni = 0; ni < 4; ++ni) {
    int n = n0 + wn4 * 64 + ni * 16 + lane16;
    float bias = fmaf(__expf(0.5f * bv[n]), be[(size_t)sg * 1024 + n], bm[n]);
#pragma unroll
    for (int mi = 0; mi < 8; ++mi) {
#pragma unroll
      for (int r = 0; r < 4; ++r) {
        int m = m0 + wm2 * 128 + mi * 16 + quad * 4 + r;
        C_s[(size_t)m * 1024 + n] = f2bf(fmaxf(acc[mi][ni][r] + bias, 0.f));
      }
    }
  }
}

// ---------- final layer: logits[s] = act2[s] @ Wl[s] + bl[s], N=10 ----------
__global__ __launch_bounds__(256) void gemm_last_k(
    const u16* __restrict__ act2, const u16* __restrict__ Wlt,
    float* __restrict__ out,
    const float* __restrict__ blm, const float* __restrict__ blv,
    const float* __restrict__ bel, int s_off) {
  __shared__ f32x4 red[4][64];
  const int b = blockIdx.x;
  const int sc = b >> 6, tile = b & 63;
  const int t = threadIdx.x;
  const int w = t >> 6, l = t & 63;
  const int quad = l >> 4, lane16 = l & 15;
  const int m0 = tile * 16;

  const u16* A_s = act2 + (size_t)sc * 1024 * 1024;
  const u16* B_s = Wlt + (size_t)sc * 16 * 1024;

  f32x4 acc = (f32x4){0.f, 0.f, 0.f, 0.f};
  const int kbase = w * 256;
#pragma unroll
  for (int k0 = 0; k0 < 256; k0 += 32) {
    int k = kbase + k0;
    bf16x8 a = *(const bf16x8*)&A_s[(size_t)(m0 + lane16) * 1024 + k + quad * 8];
    bf16x8 bb = *(const bf16x8*)&B_s[(size_t)lane16 * 1024 + k + quad * 8];
    acc = __builtin_amdgcn_mfma_f32_16x16x32_bf16(a, bb, acc, 0, 0, 0);
  }
  red[w][l] = acc;
  __syncthreads();
  if (w == 0) {
    f32x4 r = red[0][l];
#pragma unroll
    for (int ww = 1; ww < 4; ++ww) {
      f32x4 o = red[ww][l];
      r[0] += o[0]; r[1] += o[1]; r[2] += o[2]; r[3] += o[3];
    }
    int n = lane16;
    if (n < 10) {
      int sg = sc + s_off;
      float bias = fmaf(__expf(0.5f * blv[n]), bel[sg * 10 + n], blm[n]);
#pragma unroll
      for (int rr = 0; rr < 4; ++rr) {
        int m = m0 + quad * 4 + rr;
        out[((size_t)sg * 1024 + m) * 10 + n] = r[rr] + bias;
      }
    }
  }
}

// ---------- launch ----------
extern "C" void kernel_launch(void* const* d_in, const int* in_sizes, int n_in,
                              void* d_out, int out_size, void* d_ws, size_t ws_size,
                              hipStream_t stream) {
  const float* x   = (const float*)d_in[0];
  const float* wm0 = (const float*)d_in[1];
  const float* wv0 = (const float*)d_in[2];
  const float* bm0 = (const float*)d_in[3];
  const float* bv0 = (const float*)d_in[4];
  const float* wm1 = (const float*)d_in[5];
  const float* wv1 = (const float*)d_in[6];
  const float* bm1 = (const float*)d_in[7];
  const float* bv1 = (const float*)d_in[8];
  const float* wlm = (const float*)d_in[9];
  const float* wlv = (const float*)d_in[10];
  const float* blm = (const float*)d_in[11];
  const float* blv = (const float*)d_in[12];
  const float* we0 = (const float*)d_in[13];
  const float* be0 = (const float*)d_in[14];
  const float* we1 = (const float*)d_in[15];
  const float* be1 = (const float*)d_in[16];
  const float* wel = (const float*)d_in[17];
  const float* bel = (const float*)d_in[18];
  float* out = (float*)d_out;

  // workspace layout (Kp0 = 832 now)
  const size_t sz_x    = (size_t)1024 * 832 * 2;
  const size_t sz_W0t  = (size_t)1024 * 832 * 2;   // per s (13 tiles * 1024 * 64)
  const size_t sz_act  = (size_t)1024 * 1024 * 2;  // per s
  const size_t sz_Wlt  = (size_t)16 * 1024 * 2;    // per s
  const size_t per_s = sz_W0t + 3 * sz_act + sz_Wlt;

  int SC = 32;
  while (SC > 1 && sz_x + (size_t)SC * per_s + 4096 > ws_size) SC >>= 1;

  char* ws = (char*)d_ws;
  size_t off = 0;
  auto take = [&](size_t bsz) {
    char* p = ws + off;
    off = (off + bsz + 255) & ~(size_t)255;
    return p;
  };
  u16* xbf  = (u16*)take(sz_x);
  u16* W0t  = (u16*)take((size_t)SC * sz_W0t);
  u16* act1 = (u16*)take((size_t)SC * sz_act);
  u16* W1t  = (u16*)take((size_t)SC * sz_act);
  u16* act2 = (u16*)take((size_t)SC * sz_act);
  u16* Wlt  = (u16*)take((size_t)SC * sz_Wlt);

  pad_x_k<<<3328, 256, 0, stream>>>(x, xbf);

  const int KB0 = 26;   // 832 / 32  (k >= 784 zero-filled)
  const int KB1 = 32;   // 1024 / 32

  for (int s0 = 0; s0 < 32; s0 += SC) {
    // layer 0: K=784 (Kp=832), N=1024
    sample_wt_k<<<SC * KB0 * 4, 256, 0, stream>>>(
        we0 + (size_t)s0 * 784 * 1024, wm0, wv0, W0t, 784, KB0, SC);
    gemm_bt_relu<<<16 * SC, 512, 0, stream>>>(
        xbf, (size_t)0, 832, W0t, act1, 832, bm0, bv0, be0, s0, SC);
    // layer 1: K=1024, N=1024
    sample_wt_k<<<SC * KB1 * 4, 256, 0, stream>>>(
        we1 + (size_t)s0 * 1024 * 1024, wm1, wv1, W1t, 1024, KB1, SC);
    gemm_bt_relu<<<16 * SC, 512, 0, stream>>>(
        act1, (size_t)1024 * 1024, 1024, W1t, act2, 1024, bm1, bv1, be1, s0, SC);
    // last layer
    sample_wl_k<<<SC * 64, 256, 0, stream>>>(
        wel + (size_t)s0 * 1024 * 10, wlm, wlv, Wlt);
    gemm_last_k<<<64 * SC, 256, 0, stream>>>(
        act2, Wlt, out, blm, blv, bel, s0);
  }
}

// Round 2
// 560.511 us; speedup vs baseline: 1.0269x; 1.0269x over previous
//
#include <hip/hip_runtime.h>

typedef unsigned short u16;
typedef __bf16 bf16x8 __attribute__((ext_vector_type(8)));
typedef float f32x4 __attribute__((ext_vector_type(4)));
typedef u16 u16x8 __attribute__((ext_vector_type(8)));
typedef u16 u16x4 __attribute__((ext_vector_type(4)));

// ---------- helpers ----------
__device__ __forceinline__ u16 f2bf(float f) {
  unsigned u = __builtin_bit_cast(unsigned, f);
  return (u16)((u + 0x7fffu + ((u >> 16) & 1u)) >> 16);
}

__device__ __forceinline__ void async_load16(const void* g, void* l) {
  __builtin_amdgcn_global_load_lds((const __attribute__((address_space(1))) void*)g,
                                   (__attribute__((address_space(3))) void*)l,
                                   16, 0, 0);
}

// ---------- pad + cast x: (1024,784) f32 -> (1024,800) bf16 ----------
__global__ void pad_x_k(const float* __restrict__ x, u16* __restrict__ xbf) {
  int idx = blockIdx.x * 256 + threadIdx.x;          // 1024*800
  int m = idx / 800, k = idx - m * 800;
  float v = (k < 784) ? x[m * 784 + k] : 0.f;
  xbf[idx] = f2bf(v);
}

// ---------- fused sample + transpose into GEMM-tiled layout ----------
// Round-0 proven version: wt[s][kb][n][j] = sample(W[kb*32+j][n]); per-thread
// 64B fully-contiguous writes (consecutive n -> consecutive 64B lines, no
// partial-line RMW). This layout IS the BK=32 GEMM B-tile format.
__global__ __launch_bounds__(256) void sample_wt_k(
    const float* __restrict__ we,   // chunk base: (SC,K,N)
    const float* __restrict__ wm,   // (K,N)
    const float* __restrict__ wv,   // (K,N)
    u16* __restrict__ wt,           // (SC,KB,1024,32)
    int K, int KB, int SC) {
  const int N = 1024;
  const int b = blockIdx.x;
  int s, kb, nb;
  if (SC >= 8) {
    int g = b & 7, r = b >> 3, spq = SC >> 3;
    int sq = r % spq, r2 = r / spq;
    nb = r2 & 3; kb = r2 >> 2;
    s = g + sq * 8;
  } else {
    s = b % SC; int r = b / SC; nb = r & 3; kb = r >> 2;
  }
  const int t = threadIdx.x;
  const int n = nb * 256 + t;
  const int kbase = kb * 32;
  const float* we_s = we + (size_t)s * K * N;

  u16 pk[32];
#pragma unroll
  for (int jo = 0; jo < 4; ++jo) {
    float v[8];
#pragma unroll
    for (int j = 0; j < 8; ++j) {
      int k = kbase + jo * 8 + j;
      v[j] = 0.f;
      if (k < K) {
        size_t idx = (size_t)k * N + n;
        v[j] = fmaf(__expf(0.5f * wv[idx]), we_s[idx], wm[idx]);
      }
    }
#pragma unroll
    for (int j = 0; j < 8; ++j) pk[jo * 8 + j] = f2bf(v[j]);
  }
  u16* dst = wt + ((size_t)s * KB + kb) * ((size_t)N * 32) + (size_t)n * 32;
#pragma unroll
  for (int q = 0; q < 4; ++q)
    *(u16x8*)(dst + q * 8) = *(const u16x8*)(pk + q * 8);
}

// ---------- sample last-layer W -> Wlt[s][16][1024] bf16 (n>=10 zero) ----------
__global__ void sample_wl_k(const float* __restrict__ wel,  // chunk base (SC,1024,10)
                            const float* __restrict__ wlm,  // (1024,10)
                            const float* __restrict__ wlv,  // (1024,10)
                            u16* __restrict__ wlt) {        // (SC,16,1024)
  int idx = blockIdx.x * 256 + threadIdx.x;   // SC*16*1024
  int k = idx & 1023;
  int n = (idx >> 10) & 15;
  int s = idx >> 14;
  float v = 0.f;
  if (n < 10) {
    size_t i2 = ((size_t)s * 1024 + k) * 10 + n;
    size_t iw = (size_t)k * 10 + n;
    v = fmaf(__expf(0.5f * wlv[iw]), wel[i2], wlm[iw]);
  }
  wlt[idx] = f2bf(v);
}

// ---------- batched GEMM: C[s] = relu(A[s] @ W[s] + bias[s]) ----------
// 256x256 tile, BK=32, 8 waves (2M x 4N), 3-buffer LDS (96 KiB), fine-phase
// schedule (T3+T4+T5): per tile 2 phases of {ds_read subtile | issue 2
// global_load_lds for tile T+2 | barrier | lgkmcnt(0) | setprio(1) | 16 MFMA |
// setprio(0) | barrier}; tile boundary waits vmcnt(4) (T+1's loads, issued two
// tiles ago -> ~2 compute-intervals of latency slack; never vmcnt(0) in steady
// state). Staging target buffer (T+2)%3 was freed at the T-1/T boundary
// barrier, so writes never collide with in-flight reads.
// LDS swizzle for 64B rows: o ^= ((o>>7)&3)<<4, applied on the staging
// SOURCE (chunk c -> c ^ ((c>>3)&3)) and the ds_read address (both-sides
// involution, rule 21) -> ds_read_b128 at the 8-words/bank floor.
// MFMA operands swapped (bb, af): bitwise-identical sums, transposed lane
// placement -> lane holds 4 consecutive n -> 8B u16x4 C-stores that complete
// full 128B lines within a wave (kills the 3-4x write amplification).
__global__ __launch_bounds__(512, 2) void gemm_bt_relu(
    const u16* __restrict__ A, size_t strideAs, int ldA,
    const u16* __restrict__ Bt,   // (SC, Kp/32, 1024, 32) bf16 tiles
    u16* __restrict__ C,
    int Kp,
    const float* __restrict__ bm, const float* __restrict__ bv,
    const float* __restrict__ be, int s_off, int SC) {
  // buf b: A at b*16384, B at b*16384 + 8192 (u16 units); 3 bufs = 96 KiB
  __shared__ __align__(16) u16 lds[49152];

  const int b = blockIdx.x;
  int sc, tile;
  if (SC >= 8) { int g = b & 7, r = b >> 3; tile = r & 15; sc = g + ((r >> 4) << 3); }
  else         { sc = b >> 4; tile = b & 15; }
  const int sg = sc + s_off;
  const u16* A_s = A + (size_t)sc * strideAs;
  const u16* B_s = Bt + (size_t)sc * (size_t)1024 * Kp;
  u16* C_s = C + (size_t)sc * (size_t)1024 * 1024;
  const int m0 = (tile >> 2) * 256;
  const int n0 = (tile & 3) * 256;
  const int t = threadIdx.x;
  const int wid = t >> 6, lane = t & 63;
  const int quad = lane >> 4, lane16 = lane & 15;
  const int wm2 = wid >> 2, wn4 = wid & 3;
  const int NT = Kp >> 5;

  // stage A half (256x32 = 16KB = 2 loads/wave); LDS dest linear, source
  // pre-swizzled: LDS chunk c holds global chunk c ^ ((c>>3)&3).
  auto stageA = [&](int kt, int buf) {
    const int k0 = kt * 32;
#pragma unroll
    for (int j = 0; j < 2; ++j) {
      int c = j * 512 + t;
      int cl = c ^ ((c >> 3) & 3);
      const u16* src = A_s + (size_t)(m0 + (cl >> 2)) * ldA + k0 + (cl & 3) * 8;
      async_load16(src, &lds[buf * 16384 + (j * 512 + wid * 64) * 8]);
    }
  };
  auto stageB = [&](int kt, int buf) {
    const u16* Bk = B_s + (size_t)kt * (1024 * 32);
#pragma unroll
    for (int j = 0; j < 2; ++j) {
      int c = j * 512 + t;
      int cl = c ^ ((c >> 3) & 3);
      const u16* src = Bk + (size_t)(n0 + (cl >> 2)) * 32 + (cl & 3) * 8;
      async_load16(src, &lds[buf * 16384 + 8192 + (j * 512 + wid * 64) * 8]);
    }
  };

  auto rdA = [&](int buf, int mi) -> bf16x8 {
    int o = (wm2 * 128 + mi * 16 + lane16) * 64 + quad * 16;
    o ^= ((o >> 7) & 3) << 4;
    return *(const bf16x8*)((const char*)&lds[buf * 16384] + o);
  };
  auto rdB = [&](int buf, int ni) -> bf16x8 {
    int o = (wn4 * 64 + ni * 16 + lane16) * 64 + quad * 16;
    o ^= ((o >> 7) & 3) << 4;
    return *(const bf16x8*)((const char*)&lds[buf * 16384 + 8192] + o);
  };

  f32x4 acc[8][4];
#pragma unroll
  for (int i = 0; i < 8; ++i)
#pragma unroll
    for (int j = 0; j < 4; ++j) acc[i][j] = (f32x4){0.f, 0.f, 0.f, 0.f};

  // prologue: tiles 0,1 staged; wait tile 0 (4 loads of tile 1 in flight)
  stageA(0, 0); stageB(0, 0);
  stageA(1, 1); stageB(1, 1);
  asm volatile("s_waitcnt vmcnt(4)" ::: "memory");
  __builtin_amdgcn_s_barrier();

  int cur = 0;
  for (int T = 0; T < NT; ++T) {
    const int pre = (cur + 2 >= 3) ? cur - 1 : cur + 2;   // (T+2)%3
    const bool st = (T + 2 < NT);
    bf16x8 af[4], bb[4];
    // ---- phase 0: bb + af(lo), stage A of T+2, MFMA acc[0..3][*] ----
#pragma unroll
    for (int i = 0; i < 4; ++i) bb[i] = rdB(cur, i);
#pragma unroll
    for (int i = 0; i < 4; ++i) af[i] = rdA(cur, i);
    if (st) stageA(T + 2, pre);
    __builtin_amdgcn_sched_barrier(0);
    __builtin_amdgcn_s_barrier();
    asm volatile("s_waitcnt lgkmcnt(0)" ::: "memory");
    __builtin_amdgcn_sched_barrier(0);
    __builtin_amdgcn_s_setprio(1);
#pragma unroll
    for (int mi = 0; mi < 4; ++mi)
#pragma unroll
      for (int ni = 0; ni < 4; ++ni)
        acc[mi][ni] =
            __builtin_amdgcn_mfma_f32_16x16x32_bf16(bb[ni], af[mi], acc[mi][ni], 0, 0, 0);
    __builtin_amdgcn_s_setprio(0);
    __builtin_amdgcn_sched_barrier(0);
    __builtin_amdgcn_s_barrier();
    // ---- phase 1: af(hi), stage B of T+2, MFMA acc[4..7][*] ----
#pragma unroll
    for (int i = 0; i < 4; ++i) af[i] = rdA(cur, 4 + i);
    if (st) stageB(T + 2, pre);
    __builtin_amdgcn_sched_barrier(0);
    __builtin_amdgcn_s_barrier();
    asm volatile("s_waitcnt lgkmcnt(0)" ::: "memory");
    __builtin_amdgcn_sched_barrier(0);
    __builtin_amdgcn_s_setprio(1);
#pragma unroll
    for (int mi = 0; mi < 4; ++mi)
#pragma unroll
      for (int ni = 0; ni < 4; ++ni)
        acc[4 + mi][ni] =
            __builtin_amdgcn_mfma_f32_16x16x32_bf16(bb[ni], af[mi], acc[4 + mi][ni], 0, 0, 0);
    __builtin_amdgcn_s_setprio(0);
    __builtin_amdgcn_sched_barrier(0);
    // ---- tile boundary: publish T+1 (issued two tiles ago) ----
    if (T + 1 < NT) {
      if (st) asm volatile("s_waitcnt vmcnt(4)" ::: "memory");
      else    asm volatile("s_waitcnt vmcnt(0)" ::: "memory");
      __builtin_amdgcn_s_barrier();
    }
    cur = (cur + 1 >= 3) ? 0 : cur + 1;
  }

  // epilogue: lane holds C[m = ..+lane16][n = ..+quad*4+r] -> 8B stores
#pragma unroll
  for (int ni = 0; ni < 4; ++ni) {
    float bias[4];
#pragma unroll
    for (int r = 0; r < 4; ++r) {
      int n = n0 + wn4 * 64 + ni * 16 + quad * 4 + r;
      bias[r] = fmaf(__expf(0.5f * bv[n]), be[(size_t)sg * 1024 + n], bm[n]);
    }
#pragma unroll
    for (int mi = 0; mi < 8; ++mi) {
      u16x4 pk;
#pragma unroll
      for (int r = 0; r < 4; ++r)
        pk[r] = f2bf(fmaxf(acc[mi][ni][r] + bias[r], 0.f));
      int m = m0 + wm2 * 128 + mi * 16 + lane16;
      int n = n0 + wn4 * 64 + ni * 16 + quad * 4;
      *(u16x4*)&C_s[(size_t)m * 1024 + n] = pk;
    }
  }
}

// ---------- final layer: logits[s] = act2[s] @ Wl[s] + bl[s], N=10 ----------
__global__ __launch_bounds__(256) void gemm_last_k(
    const u16* __restrict__ act2, const u16* __restrict__ Wlt,
    float* __restrict__ out,
    const float* __restrict__ blm, const float* __restrict__ blv,
    const float* __restrict__ bel, int s_off) {
  __shared__ f32x4 red[4][64];
  const int b = blockIdx.x;
  const int sc = b >> 6, tile = b & 63;
  const int t = threadIdx.x;
  const int w = t >> 6, l = t & 63;
  const int quad = l >> 4, lane16 = l & 15;
  const int m0 = tile * 16;

  const u16* A_s = act2 + (size_t)sc * 1024 * 1024;
  const u16* B_s = Wlt + (size_t)sc * 16 * 1024;

  f32x4 acc = (f32x4){0.f, 0.f, 0.f, 0.f};
  const int kbase = w * 256;
#pragma unroll
  for (int k0 = 0; k0 < 256; k0 += 32) {
    int k = kbase + k0;
    bf16x8 a = *(const bf16x8*)&A_s[(size_t)(m0 + lane16) * 1024 + k + quad * 8];
    bf16x8 bb = *(const bf16x8*)&B_s[(size_t)lane16 * 1024 + k + quad * 8];
    acc = __builtin_amdgcn_mfma_f32_16x16x32_bf16(a, bb, acc, 0, 0, 0);
  }
  red[w][l] = acc;
  __syncthreads();
  if (w == 0) {
    f32x4 r = red[0][l];
#pragma unroll
    for (int ww = 1; ww < 4; ++ww) {
      f32x4 o = red[ww][l];
      r[0] += o[0]; r[1] += o[1]; r[2] += o[2]; r[3] += o[3];
    }
    int n = lane16;
    if (n < 10) {
      int sg = sc + s_off;
      float bias = fmaf(__expf(0.5f * blv[n]), bel[sg * 10 + n], blm[n]);
#pragma unroll
      for (int rr = 0; rr < 4; ++rr) {
        int m = m0 + quad * 4 + rr;
        out[((size_t)sg * 1024 + m) * 10 + n] = r[rr] + bias;
      }
    }
  }
}

// ---------- launch ----------
extern "C" void kernel_launch(void* const* d_in, const int* in_sizes, int n_in,
                              void* d_out, int out_size, void* d_ws, size_t ws_size,
                              hipStream_t stream) {
  const float* x   = (const float*)d_in[0];
  const float* wm0 = (const float*)d_in[1];
  const float* wv0 = (const float*)d_in[2];
  const float* bm0 = (const float*)d_in[3];
  const float* bv0 = (const float*)d_in[4];
  const float* wm1 = (const float*)d_in[5];
  const float* wv1 = (const float*)d_in[6];
  const float* bm1 = (const float*)d_in[7];
  const float* bv1 = (const float*)d_in[8];
  const float* wlm = (const float*)d_in[9];
  const float* wlv = (const float*)d_in[10];
  const float* blm = (const float*)d_in[11];
  const float* blv = (const float*)d_in[12];
  const float* we0 = (const float*)d_in[13];
  const float* be0 = (const float*)d_in[14];
  const float* we1 = (const float*)d_in[15];
  const float* be1 = (const float*)d_in[16];
  const float* wel = (const float*)d_in[17];
  const float* bel = (const float*)d_in[18];
  float* out = (float*)d_out;

  // workspace layout (Kp0 = 800)
  const size_t sz_x    = (size_t)1024 * 800 * 2;
  const size_t sz_W0t  = (size_t)1024 * 800 * 2;   // per s (25 tiles * 1024 * 32)
  const size_t sz_act  = (size_t)1024 * 1024 * 2;  // per s
  const size_t sz_Wlt  = (size_t)16 * 1024 * 2;    // per s
  const size_t per_s = sz_W0t + 3 * sz_act + sz_Wlt;

  int SC = 32;
  while (SC > 1 && sz_x + (size_t)SC * per_s + 4096 > ws_size) SC >>= 1;

  char* ws = (char*)d_ws;
  size_t off = 0;
  auto take = [&](size_t bsz) {
    char* p = ws + off;
    off = (off + bsz + 255) & ~(size_t)255;
    return p;
  };
  u16* xbf  = (u16*)take(sz_x);
  u16* W0t  = (u16*)take((size_t)SC * sz_W0t);
  u16* act1 = (u16*)take((size_t)SC * sz_act);
  u16* W1t  = (u16*)take((size_t)SC * sz_act);
  u16* act2 = (u16*)take((size_t)SC * sz_act);
  u16* Wlt  = (u16*)take((size_t)SC * sz_Wlt);

  pad_x_k<<<3200, 256, 0, stream>>>(x, xbf);

  const int KB0 = 25;   // 800 / 32
  const int KB1 = 32;   // 1024 / 32

  for (int s0 = 0; s0 < 32; s0 += SC) {
    // layer 0: K=784 (Kp=800), N=1024
    sample_wt_k<<<SC * KB0 * 4, 256, 0, stream>>>(
        we0 + (size_t)s0 * 784 * 1024, wm0, wv0, W0t, 784, KB0, SC);
    gemm_bt_relu<<<16 * SC, 512, 0, stream>>>(
        xbf, (size_t)0, 800, W0t, act1, 800, bm0, bv0, be0, s0, SC);
    // layer 1: K=1024, N=1024
    sample_wt_k<<<SC * KB1 * 4, 256, 0, stream>>>(
        we1 + (size_t)s0 * 1024 * 1024, wm1, wv1, W1t, 1024, KB1, SC);
    gemm_bt_relu<<<16 * SC, 512, 0, stream>>>(
        act1, (size_t)1024 * 1024, 1024, W1t, act2, 1024, bm1, bv1, be1, s0, SC);
    // last layer
    sample_wl_k<<<SC * 64, 256, 0, stream>>>(
        wel + (size_t)s0 * 1024 * 10, wlm, wlv, Wlt);
    gemm_last_k<<<64 * SC, 256, 0, stream>>>(
        act2, Wlt, out, blm, blv, bel, s0);
  }
}

// Round 3
// 520.980 us; speedup vs baseline: 1.1048x; 1.0759x over previous
//
#include <hip/hip_runtime.h>

typedef unsigned short u16;
typedef __bf16 bf16x8 __attribute__((ext_vector_type(8)));
typedef float f32x4 __attribute__((ext_vector_type(4)));
typedef u16 u16x8 __attribute__((ext_vector_type(8)));
typedef u16 u16x4 __attribute__((ext_vector_type(4)));

// ---------- helpers ----------
__device__ __forceinline__ u16 f2bf(float f) {
  unsigned u = __builtin_bit_cast(unsigned, f);
  return (u16)((u + 0x7fffu + ((u >> 16) & 1u)) >> 16);
}

__device__ __forceinline__ void async_load16(const void* g, void* l) {
  __builtin_amdgcn_global_load_lds((const __attribute__((address_space(1))) void*)g,
                                   (__attribute__((address_space(3))) void*)l,
                                   16, 0, 0);
}

// ---------- pad + cast x: (1024,784) f32 -> (1024,800) bf16 ----------
__global__ void pad_x_k(const float* __restrict__ x, u16* __restrict__ xbf) {
  int idx = blockIdx.x * 256 + threadIdx.x;          // 1024*800
  int m = idx / 800, k = idx - m * 800;
  float v = (k < 784) ? x[m * 784 + k] : 0.f;
  xbf[idx] = f2bf(v);
}

// ---------- fused sample + transpose into GEMM-tiled layout ----------
// wt[s][kb][n][j] = sample(W[kb*32+j][n]); per-thread 64B contiguous writes.
__global__ __launch_bounds__(256) void sample_wt_k(
    const float* __restrict__ we,   // chunk base: (SC,K,N)
    const float* __restrict__ wm,   // (K,N)
    const float* __restrict__ wv,   // (K,N)
    u16* __restrict__ wt,           // (SC,KB,1024,32)
    int K, int KB, int SC) {
  const int N = 1024;
  const int b = blockIdx.x;
  int s, kb, nb;
  if (SC >= 8) {
    int g = b & 7, r = b >> 3, spq = SC >> 3;
    int sq = r % spq, r2 = r / spq;
    nb = r2 & 3; kb = r2 >> 2;
    s = g + sq * 8;
  } else {
    s = b % SC; int r = b / SC; nb = r & 3; kb = r >> 2;
  }
  const int t = threadIdx.x;
  const int n = nb * 256 + t;
  const int kbase = kb * 32;
  const float* we_s = we + (size_t)s * K * N;

  u16 pk[32];
#pragma unroll
  for (int jo = 0; jo < 4; ++jo) {
    float v[8];
#pragma unroll
    for (int j = 0; j < 8; ++j) {
      int k = kbase + jo * 8 + j;
      v[j] = 0.f;
      if (k < K) {
        size_t idx = (size_t)k * N + n;
        v[j] = fmaf(__expf(0.5f * wv[idx]), we_s[idx], wm[idx]);
      }
    }
#pragma unroll
    for (int j = 0; j < 8; ++j) pk[jo * 8 + j] = f2bf(v[j]);
  }
  u16* dst = wt + ((size_t)s * KB + kb) * ((size_t)N * 32) + (size_t)n * 32;
#pragma unroll
  for (int q = 0; q < 4; ++q)
    *(u16x8*)(dst + q * 8) = *(const u16x8*)(pk + q * 8);
}

// ---------- sample last-layer W -> Wlt[s][16][1024] bf16 (n>=10 zero) ----------
__global__ void sample_wl_k(const float* __restrict__ wel,  // chunk base (SC,1024,10)
                            const float* __restrict__ wlm,  // (1024,10)
                            const float* __restrict__ wlv,  // (1024,10)
                            u16* __restrict__ wlt) {        // (SC,16,1024)
  int idx = blockIdx.x * 256 + threadIdx.x;   // SC*16*1024
  int k = idx & 1023;
  int n = (idx >> 10) & 15;
  int s = idx >> 14;
  float v = 0.f;
  if (n < 10) {
    size_t i2 = ((size_t)s * 1024 + k) * 10 + n;
    size_t iw = (size_t)k * 10 + n;
    v = fmaf(__expf(0.5f * wlv[iw]), wel[i2], wlm[iw]);
  }
  wlt[idx] = f2bf(v);
}

// ---------- batched GEMM: C[s] = relu(A[s] @ W[s] + bias[s]) ----------
// 256x256 tile, BK=32, 8 waves (2M x 4N), 3-buffer LDS, fine-phase schedule
// (unchanged from round 2). NEW (round 3): epilogue routes C through LDS so
// every 128B output line is written exactly once, completely, by contiguous
// u16x8 wave stores (round-2 direct 8B fragment stores caused 4x HBM write
// amplification: WRITE_SIZE 133MB vs 33.5MB useful -> the invariant ~100us
// across three different K-loop schedules).
__global__ __launch_bounds__(512, 2) void gemm_bt_relu(
    const u16* __restrict__ A, size_t strideAs, int ldA,
    const u16* __restrict__ Bt,   // (SC, Kp/32, 1024, 32) bf16 tiles
    u16* __restrict__ C,
    int Kp,
    const float* __restrict__ bm, const float* __restrict__ bv,
    const float* __restrict__ be, int s_off, int SC) {
  // buf b: A at b*16384, B at b*16384 + 8192 (u16 units); 3 bufs = 96 KiB
  __shared__ __align__(16) u16 lds[49152];

  const int b = blockIdx.x;
  int sc, tile;
  if (SC >= 8) { int g = b & 7, r = b >> 3; tile = r & 15; sc = g + ((r >> 4) << 3); }
  else         { sc = b >> 4; tile = b & 15; }
  const int sg = sc + s_off;
  const u16* A_s = A + (size_t)sc * strideAs;
  const u16* B_s = Bt + (size_t)sc * (size_t)1024 * Kp;
  u16* C_s = C + (size_t)sc * (size_t)1024 * 1024;
  const int m0 = (tile >> 2) * 256;
  const int n0 = (tile & 3) * 256;
  const int t = threadIdx.x;
  const int wid = t >> 6, lane = t & 63;
  const int quad = lane >> 4, lane16 = lane & 15;
  const int wm2 = wid >> 2, wn4 = wid & 3;
  const int NT = Kp >> 5;

  auto stageA = [&](int kt, int buf) {
    const int k0 = kt * 32;
#pragma unroll
    for (int j = 0; j < 2; ++j) {
      int c = j * 512 + t;
      int cl = c ^ ((c >> 3) & 3);
      const u16* src = A_s + (size_t)(m0 + (cl >> 2)) * ldA + k0 + (cl & 3) * 8;
      async_load16(src, &lds[buf * 16384 + (j * 512 + wid * 64) * 8]);
    }
  };
  auto stageB = [&](int kt, int buf) {
    const u16* Bk = B_s + (size_t)kt * (1024 * 32);
#pragma unroll
    for (int j = 0; j < 2; ++j) {
      int c = j * 512 + t;
      int cl = c ^ ((c >> 3) & 3);
      const u16* src = Bk + (size_t)(n0 + (cl >> 2)) * 32 + (cl & 3) * 8;
      async_load16(src, &lds[buf * 16384 + 8192 + (j * 512 + wid * 64) * 8]);
    }
  };

  auto rdA = [&](int buf, int mi) -> bf16x8 {
    int o = (wm2 * 128 + mi * 16 + lane16) * 64 + quad * 16;
    o ^= ((o >> 7) & 3) << 4;
    return *(const bf16x8*)((const char*)&lds[buf * 16384] + o);
  };
  auto rdB = [&](int buf, int ni) -> bf16x8 {
    int o = (wn4 * 64 + ni * 16 + lane16) * 64 + quad * 16;
    o ^= ((o >> 7) & 3) << 4;
    return *(const bf16x8*)((const char*)&lds[buf * 16384 + 8192] + o);
  };

  f32x4 acc[8][4];
#pragma unroll
  for (int i = 0; i < 8; ++i)
#pragma unroll
    for (int j = 0; j < 4; ++j) acc[i][j] = (f32x4){0.f, 0.f, 0.f, 0.f};

  // prologue: tiles 0,1 staged; wait tile 0 (4 loads of tile 1 in flight)
  stageA(0, 0); stageB(0, 0);
  stageA(1, 1); stageB(1, 1);
  asm volatile("s_waitcnt vmcnt(4)" ::: "memory");
  __builtin_amdgcn_s_barrier();

  int cur = 0;
  for (int T = 0; T < NT; ++T) {
    const int pre = (cur + 2 >= 3) ? cur - 1 : cur + 2;   // (T+2)%3
    const bool st = (T + 2 < NT);
    bf16x8 af[4], bb[4];
    // ---- phase 0: bb + af(lo), stage A of T+2, MFMA acc[0..3][*] ----
#pragma unroll
    for (int i = 0; i < 4; ++i) bb[i] = rdB(cur, i);
#pragma unroll
    for (int i = 0; i < 4; ++i) af[i] = rdA(cur, i);
    if (st) stageA(T + 2, pre);
    __builtin_amdgcn_sched_barrier(0);
    __builtin_amdgcn_s_barrier();
    asm volatile("s_waitcnt lgkmcnt(0)" ::: "memory");
    __builtin_amdgcn_sched_barrier(0);
    __builtin_amdgcn_s_setprio(1);
#pragma unroll
    for (int mi = 0; mi < 4; ++mi)
#pragma unroll
      for (int ni = 0; ni < 4; ++ni)
        acc[mi][ni] =
            __builtin_amdgcn_mfma_f32_16x16x32_bf16(bb[ni], af[mi], acc[mi][ni], 0, 0, 0);
    __builtin_amdgcn_s_setprio(0);
    __builtin_amdgcn_sched_barrier(0);
    __builtin_amdgcn_s_barrier();
    // ---- phase 1: af(hi), stage B of T+2, MFMA acc[4..7][*] ----
#pragma unroll
    for (int i = 0; i < 4; ++i) af[i] = rdA(cur, 4 + i);
    if (st) stageB(T + 2, pre);
    __builtin_amdgcn_sched_barrier(0);
    __builtin_amdgcn_s_barrier();
    asm volatile("s_waitcnt lgkmcnt(0)" ::: "memory");
    __builtin_amdgcn_sched_barrier(0);
    __builtin_amdgcn_s_setprio(1);
#pragma unroll
    for (int mi = 0; mi < 4; ++mi)
#pragma unroll
      for (int ni = 0; ni < 4; ++ni)
        acc[4 + mi][ni] =
            __builtin_amdgcn_mfma_f32_16x16x32_bf16(bb[ni], af[mi], acc[4 + mi][ni], 0, 0, 0);
    __builtin_amdgcn_s_setprio(0);
    __builtin_amdgcn_sched_barrier(0);
    // ---- tile boundary: publish T+1 (issued two tiles ago) ----
    if (T + 1 < NT) {
      if (st) asm volatile("s_waitcnt vmcnt(4)" ::: "memory");
      else    asm volatile("s_waitcnt vmcnt(0)" ::: "memory");
      __builtin_amdgcn_s_barrier();
    }
    cur = (cur + 1 >= 3) ? 0 : cur + 1;
  }

  // ---- epilogue v3: bias+relu, transpose through LDS, full-line stores ----
  // acc layout (swapped operands): value (mi,ni,r) is
  //   C[m0 + wm2*128 + mi*16 + lane16][n0 + wn4*64 + ni*16 + quad*4 + r].
  // Panel loop q=0..3: wave-group wm2 writes its rows [wm2*128+q*32, +32)
  // into LDS panel [32][264] bf16 (264 = 256 + 8 pad -> b64 writes at the
  // 4-cyc LDS floor, no extra conflicts). Then all 512 threads store both
  // panels as u16x8: 32 lanes cover one 512B row segment contiguously ->
  // every 128B line written once, fully.
  float bias[4][4];
#pragma unroll
  for (int ni = 0; ni < 4; ++ni)
#pragma unroll
    for (int r = 0; r < 4; ++r) {
      int n = n0 + wn4 * 64 + ni * 16 + quad * 4 + r;
      bias[ni][r] = fmaf(__expf(0.5f * bv[n]), be[(size_t)sg * 1024 + n], bm[n]);
    }

  __syncthreads();   // all waves done reading K-loop LDS buffers
  const int PAN = 8448;  // 32 * 264 u16 per panel
  for (int q = 0; q < 4; ++q) {
#pragma unroll
    for (int dmi = 0; dmi < 2; ++dmi) {
      int mi = q * 2 + dmi;
      int r_loc = dmi * 16 + lane16;
#pragma unroll
      for (int ni = 0; ni < 4; ++ni) {
        u16x4 pk;
#pragma unroll
        for (int r = 0; r < 4; ++r)
          pk[r] = f2bf(fmaxf(acc[mi][ni][r] + bias[ni][r], 0.f));
        int col = wn4 * 64 + ni * 16 + quad * 4;
        *(u16x4*)&lds[wm2 * PAN + r_loc * 264 + col] = pk;
      }
    }
    __syncthreads();
#pragma unroll
    for (int ps = 0; ps < 4; ++ps) {
      int j = ps * 512 + t;        // 0..2047: 2 panels * 32 rows * 32 chunks
      int g = j >> 10;             // which wave-group band
      int row = (j & 1023) >> 5;   // 0..31
      int ch = j & 31;             // 16B chunk within 512B row segment
      u16x8 v = *(const u16x8*)&lds[g * PAN + row * 264 + ch * 8];
      int m = m0 + g * 128 + q * 32 + row;
      *(u16x8*)&C_s[(size_t)m * 1024 + n0 + ch * 8] = v;
    }
    __syncthreads();
  }
}

// ---------- final layer: logits[s] = act2[s] @ Wl[s] + bl[s], N=10 ----------
__global__ __launch_bounds__(256) void gemm_last_k(
    const u16* __restrict__ act2, const u16* __restrict__ Wlt,
    float* __restrict__ out,
    const float* __restrict__ blm, const float* __restrict__ blv,
    const float* __restrict__ bel, int s_off) {
  __shared__ f32x4 red[4][64];
  const int b = blockIdx.x;
  const int sc = b >> 6, tile = b & 63;
  const int t = threadIdx.x;
  const int w = t >> 6, l = t & 63;
  const int quad = l >> 4, lane16 = l & 15;
  const int m0 = tile * 16;

  const u16* A_s = act2 + (size_t)sc * 1024 * 1024;
  const u16* B_s = Wlt + (size_t)sc * 16 * 1024;

  f32x4 acc = (f32x4){0.f, 0.f, 0.f, 0.f};
  const int kbase = w * 256;
#pragma unroll
  for (int k0 = 0; k0 < 256; k0 += 32) {
    int k = kbase + k0;
    bf16x8 a = *(const bf16x8*)&A_s[(size_t)(m0 + lane16) * 1024 + k + quad * 8];
    bf16x8 bb = *(const bf16x8*)&B_s[(size_t)lane16 * 1024 + k + quad * 8];
    acc = __builtin_amdgcn_mfma_f32_16x16x32_bf16(a, bb, acc, 0, 0, 0);
  }
  red[w][l] = acc;
  __syncthreads();
  if (w == 0) {
    f32x4 r = red[0][l];
#pragma unroll
    for (int ww = 1; ww < 4; ++ww) {
      f32x4 o = red[ww][l];
      r[0] += o[0]; r[1] += o[1]; r[2] += o[2]; r[3] += o[3];
    }
    int n = lane16;
    if (n < 10) {
      int sg = sc + s_off;
      float bias = fmaf(__expf(0.5f * blv[n]), bel[sg * 10 + n], blm[n]);
#pragma unroll
      for (int rr = 0; rr < 4; ++rr) {
        int m = m0 + quad * 4 + rr;
        out[((size_t)sg * 1024 + m) * 10 + n] = r[rr] + bias;
      }
    }
  }
}

// ---------- launch ----------
extern "C" void kernel_launch(void* const* d_in, const int* in_sizes, int n_in,
                              void* d_out, int out_size, void* d_ws, size_t ws_size,
                              hipStream_t stream) {
  const float* x   = (const float*)d_in[0];
  const float* wm0 = (const float*)d_in[1];
  const float* wv0 = (const float*)d_in[2];
  const float* bm0 = (const float*)d_in[3];
  const float* bv0 = (const float*)d_in[4];
  const float* wm1 = (const float*)d_in[5];
  const float* wv1 = (const float*)d_in[6];
  const float* bm1 = (const float*)d_in[7];
  const float* bv1 = (const float*)d_in[8];
  const float* wlm = (const float*)d_in[9];
  const float* wlv = (const float*)d_in[10];
  const float* blm = (const float*)d_in[11];
  const float* blv = (const float*)d_in[12];
  const float* we0 = (const float*)d_in[13];
  const float* be0 = (const float*)d_in[14];
  const float* we1 = (const float*)d_in[15];
  const float* be1 = (const float*)d_in[16];
  const float* wel = (const float*)d_in[17];
  const float* bel = (const float*)d_in[18];
  float* out = (float*)d_out;

  // workspace layout (Kp0 = 800)
  const size_t sz_x    = (size_t)1024 * 800 * 2;
  const size_t sz_W0t  = (size_t)1024 * 800 * 2;   // per s (25 tiles * 1024 * 32)
  const size_t sz_act  = (size_t)1024 * 1024 * 2;  // per s
  const size_t sz_Wlt  = (size_t)16 * 1024 * 2;    // per s
  const size_t per_s = sz_W0t + 3 * sz_act + sz_Wlt;

  int SC = 32;
  while (SC > 1 && sz_x + (size_t)SC * per_s + 4096 > ws_size) SC >>= 1;

  char* ws = (char*)d_ws;
  size_t off = 0;
  auto take = [&](size_t bsz) {
    char* p = ws + off;
    off = (off + bsz + 255) & ~(size_t)255;
    return p;
  };
  u16* xbf  = (u16*)take(sz_x);
  u16* W0t  = (u16*)take((size_t)SC * sz_W0t);
  u16* act1 = (u16*)take((size_t)SC * sz_act);
  u16* W1t  = (u16*)take((size_t)SC * sz_act);
  u16* act2 = (u16*)take((size_t)SC * sz_act);
  u16* Wlt  = (u16*)take((size_t)SC * sz_Wlt);

  pad_x_k<<<3200, 256, 0, stream>>>(x, xbf);

  const int KB0 = 25;   // 800 / 32
  const int KB1 = 32;   // 1024 / 32

  for (int s0 = 0; s0 < 32; s0 += SC) {
    // layer 0: K=784 (Kp=800), N=1024
    sample_wt_k<<<SC * KB0 * 4, 256, 0, stream>>>(
        we0 + (size_t)s0 * 784 * 1024, wm0, wv0, W0t, 784, KB0, SC);
    gemm_bt_relu<<<16 * SC, 512, 0, stream>>>(
        xbf, (size_t)0, 800, W0t, act1, 800, bm0, bv0, be0, s0, SC);
    // layer 1: K=1024, N=1024
    sample_wt_k<<<SC * KB1 * 4, 256, 0, stream>>>(
        we1 + (size_t)s0 * 1024 * 1024, wm1, wv1, W1t, 1024, KB1, SC);
    gemm_bt_relu<<<16 * SC, 512, 0, stream>>>(
        act1, (size_t)1024 * 1024, 1024, W1t, act2, 1024, bm1, bv1, be1, s0, SC);
    // last layer
    sample_wl_k<<<SC * 64, 256, 0, stream>>>(
        wel + (size_t)s0 * 1024 * 10, wlm, wlv, Wlt);
    gemm_last_k<<<64 * SC, 256, 0, stream>>>(
        act2, Wlt, out, blm, blv, bel, s0);
  }
}